// Round 1
// baseline (204.146 us; speedup 1.0000x reference)
//
#include <hip/hip_runtime.h>
#include <hip/hip_bf16.h>

// TFMBSLinear forward on MI355X:
//   out[b][o] = sum_k sign(x[b][k]) * sign(w[o][k]) + bias[o]
// Strategy: sign-quantize x and w to bf16 {-1,0,+1} (exact), then bf16 MFMA
// GEMM (m97 structure: 128x128 tile, 16x16x32 MFMA, global_load_lds width=16).
// All arithmetic is exact (integer sums <= 2048 in fp32 accum), so the result
// is bit-identical to the fp32 reference.

typedef __bf16 bf16x8 __attribute__((ext_vector_type(8)));
typedef float floatx4 __attribute__((ext_vector_type(4)));

static constexpr int M = 8192;   // batch
static constexpr int N = 2048;   // out features
static constexpr int K = 2048;   // in features
static constexpr int BM = 128, BN = 128, BK = 32;

// ---------------- quantize: fp32 -> sign as bf16 bits ----------------
__device__ __forceinline__ unsigned short sgn_bits(float v) {
    // +1.0 bf16 = 0x3F80, -1.0 bf16 = 0xBF80, sign(0) = 0 (handles +-0.0)
    unsigned u = __float_as_uint(v);
    return (v == 0.0f) ? (unsigned short)0
                       : (unsigned short)(0x3F80u | ((u >> 16) & 0x8000u));
}

__global__ __launch_bounds__(256) void quant_sign(const float4* __restrict__ in,
                                                  ushort4* __restrict__ out,
                                                  int n4) {
    int i = blockIdx.x * 256 + threadIdx.x;
    if (i >= n4) return;
    float4 v = in[i];
    ushort4 s;
    s.x = sgn_bits(v.x);
    s.y = sgn_bits(v.y);
    s.z = sgn_bits(v.z);
    s.w = sgn_bits(v.w);
    out[i] = s;
}

// ---------------- bf16 ternary GEMM, C = A * B^T + bias ----------------
// A: [M,K] bf16 (sign(x)), B: [N,K] bf16 (sign(w)) -- both K-contiguous.
// 256 threads = 4 waves in 2x2, each wave does a 64x64 sub-tile as 4x4 MFMAs.
__global__ __launch_bounds__(256, 3) void tgemm_bt(
    const unsigned short* __restrict__ A,
    const unsigned short* __restrict__ B,
    const float* __restrict__ bias,
    float* __restrict__ C)
{
    __shared__ unsigned short sA[BM * BK];   // 8 KB, row-major [m][k]
    __shared__ unsigned short sB[BN * BK];   // 8 KB, row-major [n][k]

    const int tid  = threadIdx.x;
    const int wave = tid >> 6;
    const int lane = tid & 63;
    const int quad = lane >> 4;     // 0..3
    const int l16  = lane & 15;

    const int bm = blockIdx.x * BM;
    const int bn = blockIdx.y * BN;

    // Staging: tile = 128 rows x 32 (bf16) = 8 KB = 512 chunks of 16 B.
    // chunk c -> row c>>2, k-offset (c&3)*8.  Thread stages chunks tid, tid+256.
    const int c0 = tid;
    const int c1 = tid + 256;
    const unsigned short* gA0 = A + (size_t)(bm + (c0 >> 2)) * K + (c0 & 3) * 8;
    const unsigned short* gA1 = A + (size_t)(bm + (c1 >> 2)) * K + (c1 & 3) * 8;
    const unsigned short* gB0 = B + (size_t)(bn + (c0 >> 2)) * K + (c0 & 3) * 8;
    const unsigned short* gB1 = B + (size_t)(bn + (c1 >> 2)) * K + (c1 & 3) * 8;

    // LDS dests are wave-uniform; HW writes base + lane*16 (m104/m108 rule).
    unsigned short* lA0 = sA + wave * 512;          // chunks [wave*64 .. +64)
    unsigned short* lA1 = sA + 2048 + wave * 512;   // chunks [256+wave*64 ..)
    unsigned short* lB0 = sB + wave * 512;
    unsigned short* lB1 = sB + 2048 + wave * 512;

    const int wm = (wave & 1) * 64;   // wave's M offset in tile
    const int wn = (wave >> 1) * 64;  // wave's N offset in tile

    // MFMA A/B operand fragment: lane holds 8 contiguous k at row (lane&15),
    // k-base quad*8 (verified m89/m120 layout).
    const int aoff = (wm + l16) * BK + quad * 8;
    const int boff = (wn + l16) * BK + quad * 8;

    floatx4 acc[4][4] = {};

    for (int k0 = 0; k0 < K; k0 += BK) {
        __builtin_amdgcn_global_load_lds(
            (const __attribute__((address_space(1))) void*)(gA0 + k0),
            (__attribute__((address_space(3))) void*)lA0, 16, 0, 0);
        __builtin_amdgcn_global_load_lds(
            (const __attribute__((address_space(1))) void*)(gA1 + k0),
            (__attribute__((address_space(3))) void*)lA1, 16, 0, 0);
        __builtin_amdgcn_global_load_lds(
            (const __attribute__((address_space(1))) void*)(gB0 + k0),
            (__attribute__((address_space(3))) void*)lB0, 16, 0, 0);
        __builtin_amdgcn_global_load_lds(
            (const __attribute__((address_space(1))) void*)(gB1 + k0),
            (__attribute__((address_space(3))) void*)lB1, 16, 0, 0);

        __syncthreads();   // compiler inserts vmcnt(0) drain before barrier

        bf16x8 af[4], bfr[4];
        #pragma unroll
        for (int i = 0; i < 4; ++i)
            af[i] = *reinterpret_cast<const bf16x8*>(&sA[aoff + i * 16 * BK]);
        #pragma unroll
        for (int j = 0; j < 4; ++j)
            bfr[j] = *reinterpret_cast<const bf16x8*>(&sB[boff + j * 16 * BK]);

        #pragma unroll
        for (int i = 0; i < 4; ++i) {
            #pragma unroll
            for (int j = 0; j < 4; ++j) {
                acc[i][j] = __builtin_amdgcn_mfma_f32_16x16x32_bf16(
                    af[i], bfr[j], acc[i][j], 0, 0, 0);
            }
        }
        __syncthreads();   // protect LDS from next iteration's staging
    }

    // Epilogue: C/D layout (16x16x32): col = lane&15 (n), row = quad*4+reg (m).
    const int cn = bn + wn + l16;
    float bcol[4];
    #pragma unroll
    for (int j = 0; j < 4; ++j) bcol[j] = bias[cn + j * 16];

    const int cm = bm + wm + quad * 4;
    #pragma unroll
    for (int i = 0; i < 4; ++i) {
        #pragma unroll
        for (int j = 0; j < 4; ++j) {
            #pragma unroll
            for (int r = 0; r < 4; ++r) {
                C[(size_t)(cm + i * 16 + r) * N + (cn + j * 16)] =
                    acc[i][j][r] + bcol[j];
            }
        }
    }
}

extern "C" void kernel_launch(void* const* d_in, const int* in_sizes, int n_in,
                              void* d_out, int out_size, void* d_ws, size_t ws_size,
                              hipStream_t stream) {
    const float* x    = (const float*)d_in[0];   // [M,K] fp32
    const float* w    = (const float*)d_in[1];   // [N,K] fp32
    const float* bias = (const float*)d_in[2];   // [N]   fp32
    float* out = (float*)d_out;                  // [M,N] fp32

    // workspace: qx (32 MB) then qw (8 MB), bf16 bits as ushort
    unsigned short* qx = (unsigned short*)d_ws;
    unsigned short* qw = qx + (size_t)M * K;

    const int n4x = (M * K) / 4;   // 4,194,304
    const int n4w = (N * K) / 4;   // 1,048,576
    quant_sign<<<n4x / 256, 256, 0, stream>>>((const float4*)x, (ushort4*)qx, n4x);
    quant_sign<<<n4w / 256, 256, 0, stream>>>((const float4*)w, (ushort4*)qw, n4w);

    dim3 grid(M / BM, N / BN);   // 64 x 16
    tgemm_bt<<<grid, 256, 0, stream>>>(qx, qw, bias, out);
}

// Round 2
// 163.230 us; speedup vs baseline: 1.2507x; 1.2507x over previous
//
#include <hip/hip_runtime.h>
#include <hip/hip_bf16.h>

// TFMBSLinear forward on MI355X:
//   out[b][o] = sum_k sign(x[b][k]) * sign(w[o][k]) + bias[o]
// R1: int8 MFMA path. sign -> i8 {-1,0,+1}; v_mfma_i32_16x16x64_i8 runs at
// ~2x the bf16 rate with half the staging bytes. i32 accumulation is exact
// (|sum| <= 2048), i32->f32 convert exact, so output is bit-identical to ref.
// LDS k-chunk XOR swizzle cuts the 8-way ds_read_b128 bank conflict to 4-way.

typedef int intx4 __attribute__((ext_vector_type(4)));

static constexpr int M = 8192;   // batch
static constexpr int N = 2048;   // out features
static constexpr int K = 2048;   // in features
static constexpr int BM = 128, BN = 128, BK = 64;   // BK in i8 elements

// ---------------- quantize: fp32 -> sign as i8, both tensors in one launch ----
__device__ __forceinline__ unsigned sgn_b(float v) {
    // {+1, -1, 0} as a byte
    return (unsigned)(unsigned char)((v > 0.0f) ? 1 : ((v < 0.0f) ? -1 : 0));
}

__global__ __launch_bounds__(256) void quant_sign_i8(
    const float4* __restrict__ x, const float4* __restrict__ w,
    char* __restrict__ qx, char* __restrict__ qw, int nx8, int ntot8)
{
    int i = blockIdx.x * 256 + threadIdx.x;
    if (i >= ntot8) return;
    const float4* src;
    char* dst;
    if (i < nx8) { src = x + (size_t)i * 2; dst = qx + (size_t)i * 8; }
    else {
        int j = i - nx8;
        src = w + (size_t)j * 2; dst = qw + (size_t)j * 8;
    }
    float4 a = src[0], b = src[1];
    uint2 p;
    p.x = sgn_b(a.x) | (sgn_b(a.y) << 8) | (sgn_b(a.z) << 16) | (sgn_b(a.w) << 24);
    p.y = sgn_b(b.x) | (sgn_b(b.y) << 8) | (sgn_b(b.z) << 16) | (sgn_b(b.w) << 24);
    *reinterpret_cast<uint2*>(dst) = p;
}

// ---------------- i8 ternary GEMM, C = A * B^T + bias ----------------
// A: [M,K] i8 (sign(x)), B: [N,K] i8 (sign(w)) -- both K-contiguous.
// 256 threads = 4 waves in 2x2; each wave: 64x64 sub-tile as 4x4 MFMAs of
// 16x16x64. K-loop: 32 iterations of BK=64.
__global__ __launch_bounds__(256, 3) void tgemm_i8(
    const char* __restrict__ A,
    const char* __restrict__ B,
    const float* __restrict__ bias,
    float* __restrict__ C)
{
    __shared__ char sA[BM * BK];   // 8 KB, [row][k] with k-chunk XOR swizzle
    __shared__ char sB[BN * BK];   // 8 KB

    const int tid  = threadIdx.x;
    const int wave = tid >> 6;
    const int lane = tid & 63;
    const int quad = lane >> 4;     // 0..3
    const int l16  = lane & 15;

    const int bm = blockIdx.x * BM;
    const int bn = blockIdx.y * BN;

    // Staging: tile = 128 rows x 64 B = 8 KB = 512 chunks of 16 B.
    // LDS slot s holds global chunk (row = s>>2, kc = (s&3) ^ (row&3)).
    // Thread stages slots tid and tid+256 for each matrix.
    const int c0 = tid;
    const int c1 = tid + 256;
    const int r0 = c0 >> 2, kc0 = (c0 & 3) ^ (r0 & 3);
    const int r1 = c1 >> 2, kc1 = (c1 & 3) ^ (r1 & 3);
    const char* gA0 = A + (size_t)(bm + r0) * K + kc0 * 16;
    const char* gA1 = A + (size_t)(bm + r1) * K + kc1 * 16;
    const char* gB0 = B + (size_t)(bn + r0) * K + kc0 * 16;
    const char* gB1 = B + (size_t)(bn + r1) * K + kc1 * 16;

    // Wave-uniform LDS bases; HW writes lane i at base + i*16 (m104/m108).
    char* lA0 = sA + wave * 1024;
    char* lA1 = sA + 4096 + wave * 1024;
    char* lB0 = sB + wave * 1024;
    char* lB1 = sB + 4096 + wave * 1024;

    const int wm = (wave & 1) * 64;   // wave's M offset in tile
    const int wn = (wave >> 1) * 64;  // wave's N offset in tile

    // Fragment: lane holds 16 contiguous k at row (l16), k-base quad*16,
    // with the XOR swizzle applied to the k-chunk index.
    const int aoff = (wm + l16) * BK + ((quad ^ (l16 & 3)) * 16);
    const int boff = (wn + l16) * BK + ((quad ^ (l16 & 3)) * 16);

    intx4 acc[4][4] = {};

    for (int k0 = 0; k0 < K; k0 += BK) {
        __builtin_amdgcn_global_load_lds(
            (const __attribute__((address_space(1))) void*)(gA0 + k0),
            (__attribute__((address_space(3))) void*)lA0, 16, 0, 0);
        __builtin_amdgcn_global_load_lds(
            (const __attribute__((address_space(1))) void*)(gA1 + k0),
            (__attribute__((address_space(3))) void*)lA1, 16, 0, 0);
        __builtin_amdgcn_global_load_lds(
            (const __attribute__((address_space(1))) void*)(gB0 + k0),
            (__attribute__((address_space(3))) void*)lB0, 16, 0, 0);
        __builtin_amdgcn_global_load_lds(
            (const __attribute__((address_space(1))) void*)(gB1 + k0),
            (__attribute__((address_space(3))) void*)lB1, 16, 0, 0);

        __syncthreads();

        intx4 af[4], bfr[4];
        #pragma unroll
        for (int i = 0; i < 4; ++i)
            af[i] = *reinterpret_cast<const intx4*>(&sA[aoff + i * 16 * BK]);
        #pragma unroll
        for (int j = 0; j < 4; ++j)
            bfr[j] = *reinterpret_cast<const intx4*>(&sB[boff + j * 16 * BK]);

        #pragma unroll
        for (int i = 0; i < 4; ++i) {
            #pragma unroll
            for (int j = 0; j < 4; ++j) {
                acc[i][j] = __builtin_amdgcn_mfma_i32_16x16x64_i8(
                    af[i], bfr[j], acc[i][j], 0, 0, 0);
            }
        }
        __syncthreads();
    }

    // Epilogue: C/D layout (16x16): col = lane&15 (n), row = quad*4+reg (m).
    const int cn = bn + wn + l16;
    float bcol[4];
    #pragma unroll
    for (int j = 0; j < 4; ++j) bcol[j] = bias[cn + j * 16];

    const int cm = bm + wm + quad * 4;
    #pragma unroll
    for (int i = 0; i < 4; ++i) {
        #pragma unroll
        for (int j = 0; j < 4; ++j) {
            #pragma unroll
            for (int r = 0; r < 4; ++r) {
                C[(size_t)(cm + i * 16 + r) * N + (cn + j * 16)] =
                    (float)acc[i][j][r] + bcol[j];
            }
        }
    }
}

extern "C" void kernel_launch(void* const* d_in, const int* in_sizes, int n_in,
                              void* d_out, int out_size, void* d_ws, size_t ws_size,
                              hipStream_t stream) {
    const float* x    = (const float*)d_in[0];   // [M,K] fp32
    const float* w    = (const float*)d_in[1];   // [N,K] fp32
    const float* bias = (const float*)d_in[2];   // [N]   fp32
    float* out = (float*)d_out;                  // [M,N] fp32

    // workspace: qx (16 MB) then qw (4 MB), i8
    char* qx = (char*)d_ws;
    char* qw = qx + (size_t)M * K;

    const int nx8   = (M * K) / 8;              // 2,097,152
    const int ntot8 = nx8 + (N * K) / 8;        // 2,621,440
    quant_sign_i8<<<(ntot8 + 255) / 256, 256, 0, stream>>>(
        (const float4*)x, (const float4*)w, qx, qw, nx8, ntot8);

    dim3 grid(M / BM, N / BN);   // 64 x 16
    tgemm_i8<<<grid, 256, 0, stream>>>(qx, qw, bias, out);
}

// Round 3
// 146.023 us; speedup vs baseline: 1.3980x; 1.1178x over previous
//
#include <hip/hip_runtime.h>
#include <hip/hip_bf16.h>

// TFMBSLinear forward on MI355X:
//   out[b][o] = sum_k sign(x[b][k]) * sign(w[o][k]) + bias[o]
// R2: MXFP4 MFMA path. sign -> fp4 e2m1 {0x0, 0x2(+1), 0xA(-1)} packed 2/byte;
// v_mfma_scale_f32_32x32x64_f8f6f4 (fmt=4=FP4, E8M0 scale=127 => 1.0) runs at
// ~9.1 POPS ubench (2.1x i8) with half the staging bytes. fp32 accumulation of
// integer sums <= 2048 is exact -> bit-identical to the fp32 reference.

typedef int   intx4    __attribute__((ext_vector_type(4)));
typedef int   intx8    __attribute__((ext_vector_type(8)));
typedef float floatx16 __attribute__((ext_vector_type(16)));

static constexpr int M = 8192;   // batch
static constexpr int N = 2048;   // out features
static constexpr int K = 2048;   // in features
static constexpr int KB = K / 2; // bytes per fp4-packed row = 1024
static constexpr int BM = 128, BN = 128;
static constexpr int BKB = 64;   // 64 B = 128 fp4 elements per K-iter

// ---------------- quantize: fp32 -> sign as packed fp4 nibbles ----------------
__device__ __forceinline__ unsigned nib(float v) {
    // +1.0 -> 0x2, -1.0 -> 0xA, 0 -> 0x0 (e2m1; sign bit from fp32 bit31)
    unsigned u = __float_as_uint(v);
    return (v != 0.0f) ? (0x2u | ((u >> 28) & 0x8u)) : 0u;
}

__global__ __launch_bounds__(256) void quant_sign_fp4(
    const float4* __restrict__ x, const float4* __restrict__ w,
    uint2* __restrict__ qx, uint2* __restrict__ qw, int nx16, int ntot16)
{
    int i = blockIdx.x * 256 + threadIdx.x;
    if (i >= ntot16) return;
    const float4* src;
    uint2* dst;
    if (i < nx16) { src = x + (size_t)i * 4; dst = qx + i; }
    else { int j = i - nx16; src = w + (size_t)j * 4; dst = qw + j; }
    float4 v0 = src[0], v1 = src[1], v2 = src[2], v3 = src[3];
    // element 16i+j -> nibble j: byte j>>1, low nibble = even j
    unsigned lo = nib(v0.x)        | (nib(v0.y) << 4)  | (nib(v0.z) << 8)  | (nib(v0.w) << 12)
                | (nib(v1.x) << 16)| (nib(v1.y) << 20) | (nib(v1.z) << 24) | (nib(v1.w) << 28);
    unsigned hi = nib(v2.x)        | (nib(v2.y) << 4)  | (nib(v2.z) << 8)  | (nib(v2.w) << 12)
                | (nib(v3.x) << 16)| (nib(v3.y) << 20) | (nib(v3.z) << 24) | (nib(v3.w) << 28);
    *dst = make_uint2(lo, hi);
}

// ---------------- MXFP4 ternary GEMM, C = A * B^T + bias ----------------
// A: [M,KB] packed fp4 (sign(x)), B: [N,KB] packed fp4 -- K-contiguous.
// 256 threads = 4 waves in 2x2; each wave: 64x64 sub-tile as 2x2 MFMAs of
// 32x32x64 (two K-steps of 64 per BKB=128-element iter). K-loop: 16 iters.
__device__ __forceinline__ intx8 ext4(intx4 v) {
    // fp4 operands occupy the low 4 regs of the 8-reg f8f6f4 field; upper undef
    return __builtin_shufflevector(v, v, 0, 1, 2, 3, -1, -1, -1, -1);
}

__global__ __launch_bounds__(256, 3) void tgemm_fp4(
    const char* __restrict__ A,
    const char* __restrict__ B,
    const float* __restrict__ bias,
    float* __restrict__ C)
{
    __shared__ char sA[BM * BKB];   // 8 KB, [row][64B] with k-chunk XOR swizzle
    __shared__ char sB[BN * BKB];   // 8 KB

    const int tid  = threadIdx.x;
    const int wave = tid >> 6;
    const int lane = tid & 63;
    const int l32  = lane & 31;
    const int half = lane >> 5;

    const int bm = blockIdx.x * BM;
    const int bn = blockIdx.y * BN;

    // Staging: tile = 128 rows x 64 B = 8 KB = 512 chunks of 16 B.
    // LDS slot s holds global chunk (row = s>>2, kc = (s&3) ^ (row&3)).
    const int c0 = tid;
    const int c1 = tid + 256;
    const int r0 = c0 >> 2, kc0 = (c0 & 3) ^ (r0 & 3);
    const int r1 = c1 >> 2, kc1 = (c1 & 3) ^ (r1 & 3);
    const char* gA0 = A + (size_t)(bm + r0) * KB + kc0 * 16;
    const char* gA1 = A + (size_t)(bm + r1) * KB + kc1 * 16;
    const char* gB0 = B + (size_t)(bn + r0) * KB + kc0 * 16;
    const char* gB1 = B + (size_t)(bn + r1) * KB + kc1 * 16;

    // Wave-uniform LDS bases; HW writes lane i at base + i*16 (m104/m108).
    char* lA0 = sA + wave * 1024;
    char* lA1 = sA + 4096 + wave * 1024;
    char* lB0 = sB + wave * 1024;
    char* lB1 = sB + 4096 + wave * 1024;

    const int wm = (wave & 1) * 64;   // wave's M offset in tile
    const int wn = (wave >> 1) * 64;  // wave's N offset in tile

    // Fragment: 32x32x64 A-operand: lane holds 32 consecutive k (16 B) at
    // row l32, k-base half*32 elements (= half*16 B). With XOR swizzle:
    // k-step t chunk = (2t + half) ^ (l32 & 3).
    const int sw    = l32 & 3;
    const int slot0 = (0 + half) ^ sw;   // t=0
    const int slot1 = (2 + half) ^ sw;   // t=1
    const int arow  = (wm + l32) * BKB;
    const int brow  = (wn + l32) * BKB;

    floatx16 acc[2][2] = {};

    for (int kb = 0; kb < KB; kb += BKB) {
        __builtin_amdgcn_global_load_lds(
            (const __attribute__((address_space(1))) void*)(gA0 + kb),
            (__attribute__((address_space(3))) void*)lA0, 16, 0, 0);
        __builtin_amdgcn_global_load_lds(
            (const __attribute__((address_space(1))) void*)(gA1 + kb),
            (__attribute__((address_space(3))) void*)lA1, 16, 0, 0);
        __builtin_amdgcn_global_load_lds(
            (const __attribute__((address_space(1))) void*)(gB0 + kb),
            (__attribute__((address_space(3))) void*)lB0, 16, 0, 0);
        __builtin_amdgcn_global_load_lds(
            (const __attribute__((address_space(1))) void*)(gB1 + kb),
            (__attribute__((address_space(3))) void*)lB1, 16, 0, 0);

        __syncthreads();

        intx4 a0t0 = *reinterpret_cast<const intx4*>(&sA[arow        + slot0 * 16]);
        intx4 a1t0 = *reinterpret_cast<const intx4*>(&sA[arow + 2048 + slot0 * 16]);
        intx4 b0t0 = *reinterpret_cast<const intx4*>(&sB[brow        + slot0 * 16]);
        intx4 b1t0 = *reinterpret_cast<const intx4*>(&sB[brow + 2048 + slot0 * 16]);
        intx4 a0t1 = *reinterpret_cast<const intx4*>(&sA[arow        + slot1 * 16]);
        intx4 a1t1 = *reinterpret_cast<const intx4*>(&sA[arow + 2048 + slot1 * 16]);
        intx4 b0t1 = *reinterpret_cast<const intx4*>(&sB[brow        + slot1 * 16]);
        intx4 b1t1 = *reinterpret_cast<const intx4*>(&sB[brow + 2048 + slot1 * 16]);

        // cbsz=4 (A=FP4), blgp=4 (B=FP4); scale byte 127 = 2^0 = 1.0
        acc[0][0] = __builtin_amdgcn_mfma_scale_f32_32x32x64_f8f6f4(
            ext4(a0t0), ext4(b0t0), acc[0][0], 4, 4, 0, 127, 0, 127);
        acc[0][1] = __builtin_amdgcn_mfma_scale_f32_32x32x64_f8f6f4(
            ext4(a0t0), ext4(b1t0), acc[0][1], 4, 4, 0, 127, 0, 127);
        acc[1][0] = __builtin_amdgcn_mfma_scale_f32_32x32x64_f8f6f4(
            ext4(a1t0), ext4(b0t0), acc[1][0], 4, 4, 0, 127, 0, 127);
        acc[1][1] = __builtin_amdgcn_mfma_scale_f32_32x32x64_f8f6f4(
            ext4(a1t0), ext4(b1t0), acc[1][1], 4, 4, 0, 127, 0, 127);
        acc[0][0] = __builtin_amdgcn_mfma_scale_f32_32x32x64_f8f6f4(
            ext4(a0t1), ext4(b0t1), acc[0][0], 4, 4, 0, 127, 0, 127);
        acc[0][1] = __builtin_amdgcn_mfma_scale_f32_32x32x64_f8f6f4(
            ext4(a0t1), ext4(b1t1), acc[0][1], 4, 4, 0, 127, 0, 127);
        acc[1][0] = __builtin_amdgcn_mfma_scale_f32_32x32x64_f8f6f4(
            ext4(a1t1), ext4(b0t1), acc[1][0], 4, 4, 0, 127, 0, 127);
        acc[1][1] = __builtin_amdgcn_mfma_scale_f32_32x32x64_f8f6f4(
            ext4(a1t1), ext4(b1t1), acc[1][1], 4, 4, 0, 127, 0, 127);

        __syncthreads();
    }

    // Epilogue: 32x32 C/D layout: col = lane&31, row = (reg&3)+8*(reg>>2)+4*half
    const int cn0 = bn + wn + l32;
    const float bc0 = bias[cn0];
    const float bc1 = bias[cn0 + 32];
    const int rbase = bm + wm + 4 * half;

    #pragma unroll
    for (int i = 0; i < 2; ++i) {
        #pragma unroll
        for (int r = 0; r < 16; ++r) {
            const int row = rbase + 32 * i + (r & 3) + 8 * (r >> 2);
            C[(size_t)row * N + cn0]      = acc[i][0][r] + bc0;
            C[(size_t)row * N + cn0 + 32] = acc[i][1][r] + bc1;
        }
    }
}

extern "C" void kernel_launch(void* const* d_in, const int* in_sizes, int n_in,
                              void* d_out, int out_size, void* d_ws, size_t ws_size,
                              hipStream_t stream) {
    const float* x    = (const float*)d_in[0];   // [M,K] fp32
    const float* w    = (const float*)d_in[1];   // [N,K] fp32
    const float* bias = (const float*)d_in[2];   // [N]   fp32
    float* out = (float*)d_out;                  // [M,N] fp32

    // workspace: qx (8 MB) then qw (2 MB), packed fp4
    char* qx = (char*)d_ws;
    char* qw = qx + (size_t)M * KB;

    const int nx16   = (M * K) / 16;             // 1,048,576
    const int ntot16 = nx16 + (N * K) / 16;      // 1,310,720
    quant_sign_fp4<<<ntot16 / 256, 256, 0, stream>>>(
        (const float4*)x, (const float4*)w, (uint2*)qx, (uint2*)qw, nx16, ntot16);

    dim3 grid(M / BM, N / BN);   // 64 x 16
    tgemm_fp4<<<grid, 256, 0, stream>>>(qx, qw, bias, out);
}

// Round 4
// 144.601 us; speedup vs baseline: 1.4118x; 1.0098x over previous
//
#include <hip/hip_runtime.h>

// TFMBSLinear forward on MI355X:
//   out[b][o] = sum_k sign(x[b][k]) * sign(w[o][k]) + bias[o]
// R3: MXFP4 MFMA with OPERAND-ORDER workspace layout.
// qx/qw are stored tiled: [strip s = row/32][kstep c = kbyte/32][lane l][16B],
// where lane l = (k-half h = l>>5)*32 + (row r = l&31) -- exactly the
// v_mfma_scale_f32_32x32x64_f8f6f4 fp4 A/B fragment mapping (verified R2).
// => staging global_load_lds reads contiguous 1KB per wave, LDS lands in
// operand order, fragment ds_read_b128 is lane*16 contiguous: ZERO bank
// conflicts. BKB=128B (K=256/iter) halves barrier count. Math stays exact
// (fp4 {0,+-1}, fp32 accum of integer sums <= 2048) -> absmax 0.

typedef int   intx4    __attribute__((ext_vector_type(4)));
typedef int   intx8    __attribute__((ext_vector_type(8)));
typedef float floatx16 __attribute__((ext_vector_type(16)));

static constexpr int M = 8192;   // batch
static constexpr int N = 2048;   // out features
static constexpr int K = 2048;   // in features
static constexpr int KB = K / 2; // 1024 packed bytes per row
static constexpr int BM = 128, BN = 128;

// ---------------- quantize: fp32 -> sign fp4, tiled operand order ----------
__device__ __forceinline__ unsigned nib(float v) {
    // +1.0 -> 0x2, -1.0 -> 0xA, 0 -> 0x0 (e2m1)
    unsigned u = __float_as_uint(v);
    return (v != 0.0f) ? (0x2u | ((u >> 28) & 0x8u)) : 0u;
}

__device__ __forceinline__ unsigned pack8(const float4& a, const float4& b) {
    return  nib(a.x)        | (nib(a.y) << 4)  | (nib(a.z) << 8)  | (nib(a.w) << 12)
         | (nib(b.x) << 16) | (nib(b.y) << 20) | (nib(b.z) << 24) | (nib(b.w) << 28);
}

// chunk g (16B out) -> s,c,h,r: g = s*2048 + c*64 + h*32 + r
// source: row m = s*32+r, floats [(c*2+h)*32 .. +32)
__global__ __launch_bounds__(256) void quant_tile(
    const float* __restrict__ x, const float* __restrict__ w,
    uint4* __restrict__ qx, uint4* __restrict__ qw, int nx, int ntot)
{
    int g = blockIdx.x * 256 + threadIdx.x;
    if (g >= ntot) return;
    const float* src; uint4* dst; int gg;
    if (g < nx) { gg = g; src = x; dst = qx; }
    else        { gg = g - nx; src = w; dst = qw; }
    const int r = gg & 31, h = (gg >> 5) & 1, c = (gg >> 6) & 31, s = gg >> 11;
    const int m = s * 32 + r;
    const float4* p = (const float4*)(src + (size_t)m * K + (c * 2 + h) * 32);
    uint4 o;
    o.x = pack8(p[0], p[1]);
    o.y = pack8(p[2], p[3]);
    o.z = pack8(p[4], p[5]);
    o.w = pack8(p[6], p[7]);
    dst[gg] = o;   // coalesced: consecutive threads -> consecutive 16B
}

// ---------------- MXFP4 ternary GEMM, C = A * B^T + bias ----------------
// A: [M/32][32][64][16B] operand-tiled fp4 (sign x), B likewise (sign w).
// 256 threads = 4 waves 2x2; wave tile 64x64 = 2x2 accs of 32x32.
// K-loop: 8 iters of 4 ksteps (K=256 each).
__device__ __forceinline__ intx8 ext4(intx4 v) {
    return __builtin_shufflevector(v, v, 0, 1, 2, 3, -1, -1, -1, -1);
}

__global__ __launch_bounds__(256, 3) void tgemm_fp4(
    const char* __restrict__ A,
    const char* __restrict__ B,
    const float* __restrict__ bias,
    float* __restrict__ C)
{
    __shared__ char sA[16384];   // 4 strips x 4 ksteps x 1KB (operand order)
    __shared__ char sB[16384];

    const int tid  = threadIdx.x;
    const int wave = tid >> 6;
    const int lane = tid & 63;
    const int l32  = lane & 31;
    const int half = lane >> 5;

    const int bm = blockIdx.x * BM;
    const int bn = blockIdx.y * BN;

    // Staging: wave w stages strip (bm/32 + w) of A and (bn/32 + w) of B,
    // ksteps t=0..3 each iter. Global: contiguous 1KB, lane l at +l*16.
    const char* gA = A + ((size_t)(bm >> 5) + wave) * 32768 + lane * 16;
    const char* gB = B + ((size_t)(bn >> 5) + wave) * 32768 + lane * 16;
    char* lA = sA + wave * 4096;   // + t*1024 (wave-uniform)
    char* lB = sB + wave * 4096;

    const int wm = (wave & 1) * 64;
    const int wn = (wave >> 1) * 64;

    // Fragment read: block (strip_local, t) at (strip_local*4+t)*1024 + lane*16
    const int aoff = (wm >> 5) * 4096 + lane * 16;  // + i*4096 + t*1024
    const int boff = (wn >> 5) * 4096 + lane * 16;

    floatx16 acc[2][2] = {};

    for (int it = 0; it < 8; ++it) {
        const char* ga = gA + it * 4096;   // 4 ksteps * 1KB per iter
        const char* gb = gB + it * 4096;
        #pragma unroll
        for (int t = 0; t < 4; ++t) {
            __builtin_amdgcn_global_load_lds(
                (const __attribute__((address_space(1))) void*)(ga + t * 1024),
                (__attribute__((address_space(3))) void*)(lA + t * 1024), 16, 0, 0);
            __builtin_amdgcn_global_load_lds(
                (const __attribute__((address_space(1))) void*)(gb + t * 1024),
                (__attribute__((address_space(3))) void*)(lB + t * 1024), 16, 0, 0);
        }
        __syncthreads();

        #pragma unroll
        for (int t = 0; t < 4; ++t) {
            intx4 a0 = *reinterpret_cast<const intx4*>(&sA[aoff          + t * 1024]);
            intx4 a1 = *reinterpret_cast<const intx4*>(&sA[aoff + 4096   + t * 1024]);
            intx4 b0 = *reinterpret_cast<const intx4*>(&sB[boff          + t * 1024]);
            intx4 b1 = *reinterpret_cast<const intx4*>(&sB[boff + 4096   + t * 1024]);
            // cbsz=4 (A=FP4), blgp=4 (B=FP4); scale 127 = 2^0
            acc[0][0] = __builtin_amdgcn_mfma_scale_f32_32x32x64_f8f6f4(
                ext4(a0), ext4(b0), acc[0][0], 4, 4, 0, 127, 0, 127);
            acc[0][1] = __builtin_amdgcn_mfma_scale_f32_32x32x64_f8f6f4(
                ext4(a0), ext4(b1), acc[0][1], 4, 4, 0, 127, 0, 127);
            acc[1][0] = __builtin_amdgcn_mfma_scale_f32_32x32x64_f8f6f4(
                ext4(a1), ext4(b0), acc[1][0], 4, 4, 0, 127, 0, 127);
            acc[1][1] = __builtin_amdgcn_mfma_scale_f32_32x32x64_f8f6f4(
                ext4(a1), ext4(b1), acc[1][1], 4, 4, 0, 127, 0, 127);
        }
        __syncthreads();
    }

    // Epilogue: 32x32 C/D: col = lane&31, row = (reg&3)+8*(reg>>2)+4*half
    const int cn0 = bn + wn + l32;
    const float bc0 = bias[cn0];
    const float bc1 = bias[cn0 + 32];
    const int rbase = bm + wm + 4 * half;

    #pragma unroll
    for (int i = 0; i < 2; ++i) {
        #pragma unroll
        for (int r = 0; r < 16; ++r) {
            const int row = rbase + 32 * i + (r & 3) + 8 * (r >> 2);
            C[(size_t)row * N + cn0]      = acc[i][0][r] + bc0;
            C[(size_t)row * N + cn0 + 32] = acc[i][1][r] + bc1;
        }
    }
}

extern "C" void kernel_launch(void* const* d_in, const int* in_sizes, int n_in,
                              void* d_out, int out_size, void* d_ws, size_t ws_size,
                              hipStream_t stream) {
    const float* x    = (const float*)d_in[0];   // [M,K] fp32
    const float* w    = (const float*)d_in[1];   // [N,K] fp32
    const float* bias = (const float*)d_in[2];   // [N]   fp32
    float* out = (float*)d_out;                  // [M,N] fp32

    // workspace: qx (8 MB) then qw (2 MB), operand-tiled packed fp4
    char* qx = (char*)d_ws;
    char* qw = qx + (size_t)M * KB;

    const int nx   = (M * KB) / 16;              // 524,288 chunks
    const int ntot = nx + (N * KB) / 16;         // 655,360
    quant_tile<<<ntot / 256, 256, 0, stream>>>(
        x, w, (uint4*)qx, (uint4*)qw, nx, ntot);

    dim3 grid(M / BM, N / BN);   // 64 x 16
    tgemm_fp4<<<grid, 256, 0, stream>>>(qx, qw, bias, out);
}